// Round 12
// baseline (523.358 us; speedup 1.0000x reference)
//
#include <hip/hip_runtime.h>

#define NFEAT_IN 256
#define HDIM 64
#define DLAT 16
#define NC 8
#define NL 10
#define KPROP 10
#define ELLW 64
#define OVF_CAP 8192
#define NB 128          // row-range buckets
#define PERTHREAD 16
#define TILE (256 * PERTHREAD)
#define BM 64           // GEMM2 row tile
#define BM1 128         // GEMM1 row tile (8x4 micro-tile)
#define BK1 32          // GEMM k tile

__device__ __forceinline__ float softplusf(float x) {
    return (x > 20.f) ? x : log1pf(expf(x));
}

// 4 rows x 4 cols of FMAs: acc[i][j] += a_i * wv_j
__device__ __forceinline__ void fma16(float a0, float a1, float a2, float a3,
                                      const float4 wv, float acc[4][4]) {
    acc[0][0] = fmaf(a0, wv.x, acc[0][0]); acc[0][1] = fmaf(a0, wv.y, acc[0][1]);
    acc[0][2] = fmaf(a0, wv.z, acc[0][2]); acc[0][3] = fmaf(a0, wv.w, acc[0][3]);
    acc[1][0] = fmaf(a1, wv.x, acc[1][0]); acc[1][1] = fmaf(a1, wv.y, acc[1][1]);
    acc[1][2] = fmaf(a1, wv.z, acc[1][2]); acc[1][3] = fmaf(a1, wv.w, acc[1][3]);
    acc[2][0] = fmaf(a2, wv.x, acc[2][0]); acc[2][1] = fmaf(a2, wv.y, acc[2][1]);
    acc[2][2] = fmaf(a2, wv.z, acc[2][2]); acc[2][3] = fmaf(a2, wv.w, acc[2][3]);
    acc[3][0] = fmaf(a3, wv.x, acc[3][0]); acc[3][1] = fmaf(a3, wv.y, acc[3][1]);
    acc[3][2] = fmaf(a3, wv.z, acc[3][2]); acc[3][3] = fmaf(a3, wv.w, acc[3][3]);
}

// ---------------- GEMM1: x[n][256] @ W1[256][64] + b1 -> t1t[64][n] ----------
// BM1=128, 8x4 micro-tile: 32 FMA per k-step vs 8 scalar + 1 b128 LDS reads
// -> FMA-bound inner loop (was LDS-co-critical at 4x4).
__global__ __launch_bounds__(256) void k_gemm1(
        const float* __restrict__ x, const float* __restrict__ W1,
        const float* __restrict__ b1, float* __restrict__ t1t, int n) {
    __shared__ float xs[BM1][BK1 + 4];  // 128 x 36 = 18.4 KB
    __shared__ float ws[BK1][HDIM];     // 32 x 64 = 8 KB
    int t = threadIdx.x;
    int row0 = blockIdx.x * BM1;
    int tr = t >> 4, tc = t & 15;       // 16x16 thread grid; 8x4 micro-tile
    float accA[4][4], accB[4][4];       // rows tr*8..+3 and tr*8+4..+7
    float4 bv = *reinterpret_cast<const float4*>(&b1[tc * 4]);
    #pragma unroll
    for (int i = 0; i < 4; ++i) {
        accA[i][0] = bv.x; accA[i][1] = bv.y; accA[i][2] = bv.z; accA[i][3] = bv.w;
        accB[i][0] = bv.x; accB[i][1] = bv.y; accB[i][2] = bv.z; accB[i][3] = bv.w;
    }
    for (int k0 = 0; k0 < NFEAT_IN; k0 += BK1) {
        __syncthreads();
        // stage x tile: 128 rows x 32 k = 1024 float4, 4 iters
        #pragma unroll
        for (int it = 0; it < 4; ++it) {
            int i = it * 256 + t;
            int row = i >> 3, qq = i & 7;
            int grow = row0 + row;
            float4 v = make_float4(0.f, 0.f, 0.f, 0.f);
            if (grow < n)
                v = *reinterpret_cast<const float4*>(
                        &x[(size_t)grow * NFEAT_IN + k0 + qq * 4]);
            *reinterpret_cast<float4*>(&xs[row][qq * 4]) = v;
        }
        #pragma unroll
        for (int it = 0; it < 2; ++it) {
            int i = it * 256 + t;
            int kk = i >> 4, qq = i & 15;
            *reinterpret_cast<float4*>(&ws[kk][qq * 4]) =
                *reinterpret_cast<const float4*>(&W1[(size_t)(k0 + kk) * HDIM + qq * 4]);
        }
        __syncthreads();
        #pragma unroll 4
        for (int kk = 0; kk < BK1; ++kk) {
            float4 w = *reinterpret_cast<const float4*>(&ws[kk][tc * 4]);
            float a0 = xs[tr * 8 + 0][kk];
            float a1 = xs[tr * 8 + 1][kk];
            float a2 = xs[tr * 8 + 2][kk];
            float a3 = xs[tr * 8 + 3][kk];
            fma16(a0, a1, a2, a3, w, accA);
            float a4 = xs[tr * 8 + 4][kk];
            float a5 = xs[tr * 8 + 5][kk];
            float a6 = xs[tr * 8 + 6][kk];
            float a7 = xs[tr * 8 + 7][kk];
            fma16(a4, a5, a6, a7, w, accB);
        }
    }
    int r = row0 + tr * 8;
    if (r < n) {
        #pragma unroll
        for (int cj = 0; cj < 4; ++cj) {
            int j = tc * 4 + cj;
            float4 vA = make_float4(accA[0][cj], accA[1][cj], accA[2][cj], accA[3][cj]);
            float4 vB = make_float4(accB[0][cj], accB[1][cj], accB[2][cj], accB[3][cj]);
            *reinterpret_cast<float4*>(&t1t[(size_t)j * n + r]) = vA;
            *reinterpret_cast<float4*>(&t1t[(size_t)j * n + r + 4]) = vB;
        }
    }
}

// ---------------- GEMM2: relu(bn1(t1)) @ W2 + b2 -> t2t[64][n] --------------
__global__ __launch_bounds__(256) void k_gemm2(
        const float* __restrict__ t1t, const float* __restrict__ A1,
        const float* __restrict__ B1, const float* __restrict__ W2,
        const float* __restrict__ b2, float* __restrict__ t2t, int n) {
    __shared__ float xs[BK1][BM + 4];   // 32 x 68
    __shared__ float ws[BK1][HDIM];     // 32 x 64
    __shared__ float As[HDIM], Bs[HDIM];
    int t = threadIdx.x;
    int row0 = blockIdx.x * BM;
    if (t < HDIM) { As[t] = A1[t]; Bs[t] = B1[t]; }
    int tr = t >> 4, tc = t & 15;
    float acc[4][4];
    float4 bv = *reinterpret_cast<const float4*>(&b2[tc * 4]);
    #pragma unroll
    for (int i = 0; i < 4; ++i) {
        acc[i][0] = bv.x; acc[i][1] = bv.y; acc[i][2] = bv.z; acc[i][3] = bv.w;
    }
    for (int k0 = 0; k0 < HDIM; k0 += BK1) {
        __syncthreads();
        #pragma unroll
        for (int it = 0; it < 2; ++it) {
            int i = it * 256 + t;
            int kk = i >> 4, qq = i & 15;
            float4 v = make_float4(0.f, 0.f, 0.f, 0.f);
            if (row0 + qq * 4 < n) {
                v = *reinterpret_cast<const float4*>(
                        &t1t[(size_t)(k0 + kk) * n + row0 + qq * 4]);
                float a = As[k0 + kk], b = Bs[k0 + kk];
                v.x = fmaxf(fmaf(a, v.x, b), 0.f);
                v.y = fmaxf(fmaf(a, v.y, b), 0.f);
                v.z = fmaxf(fmaf(a, v.z, b), 0.f);
                v.w = fmaxf(fmaf(a, v.w, b), 0.f);
            }
            *reinterpret_cast<float4*>(&xs[kk][qq * 4]) = v;
        }
        #pragma unroll
        for (int it = 0; it < 2; ++it) {
            int i = it * 256 + t;
            int kk = i >> 4, qq = i & 15;
            *reinterpret_cast<float4*>(&ws[kk][qq * 4]) =
                *reinterpret_cast<const float4*>(&W2[(size_t)(k0 + kk) * HDIM + qq * 4]);
        }
        __syncthreads();
        #pragma unroll 8
        for (int kk = 0; kk < BK1; ++kk) {
            float4 a = *reinterpret_cast<const float4*>(&xs[kk][tr * 4]);
            float4 w = *reinterpret_cast<const float4*>(&ws[kk][tc * 4]);
            fma16(a.x, a.y, a.z, a.w, w, acc);
        }
    }
    int r = row0 + tr * 4;
    if (r < n) {
        #pragma unroll
        for (int cj = 0; cj < 4; ++cj) {
            int j = tc * 4 + cj;
            float4 v = make_float4(acc[0][cj], acc[1][cj], acc[2][cj], acc[3][cj]);
            *reinterpret_cast<float4*>(&t2t[(size_t)j * n + r]) = v;
        }
    }
}

// per-feature sum & sumsq over transposed activations [64][n]
__global__ __launch_bounds__(256) void k_stats(
        const float* __restrict__ tt, float* __restrict__ sum,
        float* __restrict__ sq, int n) {
    int feat = blockIdx.x >> 3;
    int chunk = blockIdx.x & 7;
    const float4* p = reinterpret_cast<const float4*>(tt + (size_t)feat * n);
    int n4 = n / 4;
    float s = 0.f, q = 0.f;
    for (int i = chunk * 256 + threadIdx.x; i < n4; i += 8 * 256) {
        float4 v = p[i];
        s += v.x + v.y + v.z + v.w;
        q += v.x * v.x + v.y * v.y + v.z * v.z + v.w * v.w;
    }
    if (chunk == 0 && threadIdx.x < (n & 3)) {
        float v = tt[(size_t)feat * n + (n & ~3) + threadIdx.x];
        s += v; q += v * v;
    }
    #pragma unroll
    for (int off = 32; off; off >>= 1) {
        s += __shfl_down(s, off, 64);
        q += __shfl_down(q, off, 64);
    }
    __shared__ float ls[4], lq[4];
    int wid = threadIdx.x >> 6, lane = threadIdx.x & 63;
    if (lane == 0) { ls[wid] = s; lq[wid] = q; }
    __syncthreads();
    if (threadIdx.x == 0) {
        atomicAdd(&sum[feat], ls[0] + ls[1] + ls[2] + ls[3]);
        atomicAdd(&sq[feat],  lq[0] + lq[1] + lq[2] + lq[3]);
    }
}

__global__ void k_finalize(const float* __restrict__ sum, const float* __restrict__ sq,
        const float* __restrict__ g, const float* __restrict__ be,
        float* __restrict__ A, float* __restrict__ B, int n) {
    int j = threadIdx.x;
    if (j >= HDIM) return;
    float mean = sum[j] / (float)n;
    float var = sq[j] / (float)n - mean * mean;
    float istd = 1.0f / sqrtf(var + 1e-5f);
    A[j] = g[j] * istd;
    B[j] = be[j] - mean * istd * g[j];
}

// ---------------- z = relu(bn2(t2)) @ W3 + b3 (GEMV per node) ----------------
__global__ __launch_bounds__(256) void k_zlin(
        const float* __restrict__ t2t, const float* __restrict__ A2,
        const float* __restrict__ B2, const float* __restrict__ W3,
        const float* __restrict__ b3, float* __restrict__ out_z, int n) {
    __shared__ float As[HDIM], Bs[HDIM], Ws[HDIM * DLAT];
    int t = threadIdx.x;
    if (t < HDIM) { As[t] = A2[t]; Bs[t] = B2[t]; }
    for (int i = t; i < HDIM * DLAT; i += 256) Ws[i] = W3[i];
    __syncthreads();
    int row = blockIdx.x * 256 + t;
    if (row >= n) return;
    float z[DLAT];
    #pragma unroll
    for (int j = 0; j < DLAT; ++j) z[j] = b3[j];
    for (int k = 0; k < HDIM; ++k) {
        float hv = fmaxf(fmaf(As[k], t2t[(size_t)k * n + row], Bs[k]), 0.f);
        const float* w = &Ws[k * DLAT];
        #pragma unroll
        for (int j = 0; j < DLAT; ++j) z[j] = fmaf(hv, w[j], z[j]);
    }
    float4* zp = reinterpret_cast<float4*>(&out_z[(size_t)row * DLAT]);
    zp[0] = make_float4(z[0], z[1], z[2], z[3]);
    zp[1] = make_float4(z[4], z[5], z[6], z[7]);
    zp[2] = make_float4(z[8], z[9], z[10], z[11]);
    zp[3] = make_float4(z[12], z[13], z[14], z[15]);
}

// ---------------- radial flow: one thread per (node, class) ----------------
__global__ __launch_bounds__(256) void k_flow(
        const float* __restrict__ zbuf, const float* __restrict__ x0,
        const float* __restrict__ ap, const float* __restrict__ bp,
        const float* __restrict__ mu, const float* __restrict__ lv,
        float* __restrict__ out_logq, float* __restrict__ out_beta, int n) {
    __shared__ float a_s[NL * NC], b_s[NL * NC];
    __shared__ float x0_s[NL * NC][DLAT + 1];
    __shared__ float mu_s[NC][DLAT + 1], iv_s[NC][DLAT + 1], slv_s[NC];
    int t = threadIdx.x;
    for (int i = t; i < NL * NC; i += 256) {
        float a = softplusf(ap[i]);
        a_s[i] = a;
        b_s[i] = softplusf(bp[i]) - a;
    }
    for (int i = t; i < NL * NC * DLAT; i += 256) x0_s[i >> 4][i & 15] = x0[i];
    for (int i = t; i < NC * DLAT; i += 256) {
        mu_s[i >> 4][i & 15] = mu[i];
        iv_s[i >> 4][i & 15] = __expf(-lv[i]);
    }
    if (t < NC) {
        float s = 0.f;
        for (int d = 0; d < DLAT; ++d) s += lv[t * DLAT + d];
        slv_s[t] = s;
    }
    __syncthreads();
    int gid = blockIdx.x * 256 + t;
    int row = gid >> 3, c = gid & 7;
    if (row >= n) return;
    float zz[DLAT];
    const float4* zp = reinterpret_cast<const float4*>(&zbuf[(size_t)row * DLAT]);
    float4 z0 = zp[0], z1 = zp[1], z2 = zp[2], z3 = zp[3];
    zz[0] = z0.x; zz[1] = z0.y; zz[2] = z0.z; zz[3] = z0.w;
    zz[4] = z1.x; zz[5] = z1.y; zz[6] = z1.z; zz[7] = z1.w;
    zz[8] = z2.x; zz[9] = z2.y; zz[10] = z2.z; zz[11] = z2.w;
    zz[12] = z3.x; zz[13] = z3.y; zz[14] = z3.z; zz[15] = z3.w;

    float log_det = 0.f;
    #pragma unroll
    for (int l = NL - 1; l >= 0; --l) {
        int idx = l * NC + c;
        float a = a_s[idx], b = b_s[idx];
        const float* x0p = x0_s[idx];
        float diff[DLAT];
        float r2 = 0.f;
        #pragma unroll
        for (int d = 0; d < DLAT; ++d) {
            diff[d] = zz[d] - x0p[d];
            r2 = fmaf(diff[d], diff[d], r2);
        }
        float r = fmaxf(sqrtf(r2), 1e-8f);
        float h = 1.f / (a + r);
        float bh = b * h;
        #pragma unroll
        for (int d = 0; d < DLAT; ++d) zz[d] = fmaf(bh, diff[d], zz[d]);
        log_det += (DLAT - 1) * __logf(1.f + bh) + __logf(1.f + bh - bh * h * r);
    }
    float quad = 0.f;
    #pragma unroll
    for (int d = 0; d < DLAT; ++d) {
        float dd = zz[d] - mu_s[c][d];
        quad = fmaf(dd * dd, iv_s[c][d], quad);
    }
    float lq = -14.70301653f - 0.5f * slv_s[c] - 0.5f * quad + log_det;
    out_logq[gid] = lq;
    float w = fminf(fmaxf(lq + 20.24819398f, -30.f), 30.f);
    out_beta[gid] = __expf(w);
}

// ---------------- pass 1: radix partition edges into NB row-range buckets ----
__global__ __launch_bounds__(256) void k_bucket(
        const int* __restrict__ rows, const int* __restrict__ cols,
        int2* __restrict__ bpairs, int* __restrict__ bcnt, int cap,
        int* __restrict__ cur, int2* __restrict__ ovf, int* __restrict__ ovf_cnt,
        int e, int n, int rpb) {
    __shared__ int lcnt[NB], loff[NB], lcur[NB], gbase[NB], sc[NB];
    __shared__ int2 staged[TILE];
    int t = threadIdx.x;
    int base = blockIdx.x * TILE;
    for (int i = t; i < NB; i += 256) lcnt[i] = 0;
    __syncthreads();
    int er[PERTHREAD], ec[PERTHREAD], eb[PERTHREAD];
    #pragma unroll
    for (int k = 0; k < PERTHREAD; ++k) {
        int i = base + k * 256 + t;
        eb[k] = -1;
        if (i < e) {
            int r = rows[i], c = cols[i];
            if ((unsigned)r < (unsigned)n && (unsigned)c < (unsigned)n) {
                er[k] = r; ec[k] = c;
                int b = (int)((unsigned)r / (unsigned)rpb);
                eb[k] = b;
                atomicAdd(&lcnt[b], 1);
            }
        }
    }
    __syncthreads();
    if (t < NB) sc[t] = lcnt[t];
    __syncthreads();
    for (int off = 1; off < NB; off <<= 1) {
        int v = 0;
        if (t < NB && t >= off) v = sc[t - off];
        __syncthreads();
        if (t < NB) sc[t] += v;
        __syncthreads();
    }
    if (t < NB) { loff[t] = sc[t] - lcnt[t]; lcur[t] = sc[t] - lcnt[t]; }
    __syncthreads();
    #pragma unroll
    for (int k = 0; k < PERTHREAD; ++k) {
        if (eb[k] >= 0) {
            int slot = atomicAdd(&lcur[eb[k]], 1);
            staged[slot] = make_int2(er[k], ec[k]);
        }
    }
    __syncthreads();
    if (t < NB && lcnt[t] > 0) gbase[t] = atomicAdd(&bcnt[t], lcnt[t]);
    __syncthreads();
    int wid = t >> 6, lane = t & 63;
    for (int b = wid; b < NB; b += 4) {
        int cnt = lcnt[b];
        if (!cnt) continue;
        int gb = gbase[b], lo = loff[b];
        for (int k = lane; k < cnt; k += 64) {
            int2 p = staged[lo + k];
            int dst = gb + k;
            if (dst < cap) {
                bpairs[(size_t)b * cap + dst] = p;
            } else {
                int o = atomicAdd(ovf_cnt, 1);
                if (o < OVF_CAP) ovf[o] = p;
                atomicAdd(&cur[p.x], 1);
            }
        }
    }
}

// ---------------- pass 2: per-bucket ELL placement (L2-local writes) --------
__global__ __launch_bounds__(256) void k_build(
        const int2* __restrict__ bpairs, const int* __restrict__ bcnt, int cap,
        int* __restrict__ ecol, int* __restrict__ cur,
        int2* __restrict__ ovf, int* __restrict__ ovf_cnt, int n, int rpb) {
    __shared__ int lcnt[1024];
    int b = blockIdx.x, t = threadIdx.x;
    int row_base = b * rpb;
    int nrows = n - row_base; if (nrows > rpb) nrows = rpb;
    if (nrows <= 0) return;
    for (int i = t; i < nrows; i += 256) lcnt[i] = 0;
    __syncthreads();
    int m = bcnt[b]; if (m > cap) m = cap;
    const int2* bp = bpairs + (size_t)b * cap;
    for (int i = t; i < m; i += 256) {
        int2 p = bp[i];
        int lr = p.x - row_base;
        int j = atomicAdd(&lcnt[lr], 1);
        if (j < ELLW) {
            ecol[(size_t)p.x * ELLW + j] = p.y;
        } else {
            int o = atomicAdd(ovf_cnt, 1);
            if (o < OVF_CAP) ovf[o] = p;
        }
    }
    __syncthreads();
    for (int i = t; i < nrows; i += 256) {
        int c = lcnt[i];
        if (c) cur[row_base + i] += c;
    }
}

__global__ void k_dis(const int* __restrict__ cur, float* __restrict__ dis, int n) {
    int i = blockIdx.x * blockDim.x + threadIdx.x;
    if (i < n) dis[i] = rsqrtf((float)cur[i] + 1.0f);   // +1 = self loop
}

__global__ void k_init_hs(const float* __restrict__ beta, const float* __restrict__ dis,
                          float* __restrict__ hs, int n) {
    int i = blockIdx.x * blockDim.x + threadIdx.x;
    if (i >= n) return;
    float d = dis[i];
    const float4* b = reinterpret_cast<const float4*>(beta + (size_t)i * NC);
    float4* o = reinterpret_cast<float4*>(hs + (size_t)i * NC);
    float4 b0 = b[0], b1 = b[1];
    o[0] = make_float4(d * b0.x, d * b0.y, d * b0.z, d * b0.w);
    o[1] = make_float4(d * b1.x, d * b1.y, d * b1.z, d * b1.w);
}

// ---------------- APPNP gather iteration (8 lanes/row, hs-only state) -------
__global__ __launch_bounds__(256) void k_gather(
        const int* __restrict__ cur, const int* __restrict__ ecol,
        const float* __restrict__ hs_in, const float* __restrict__ beta,
        const float* __restrict__ dis, float* __restrict__ hs_out,
        const int2* __restrict__ ovf, const int* __restrict__ ovf_cnt, int n) {
    int row = (blockIdx.x * blockDim.x + threadIdx.x) >> 3;
    int c = threadIdx.x & 7;
    if (row >= n) return;
    int cnt = cur[row];
    int lim = cnt < ELLW ? cnt : ELLW;
    float d = dis[row];
    const int* ec = ecol + (size_t)row * ELLW;
    const int4* ec4 = reinterpret_cast<const int4*>(ec);
    float acc = hs_in[row * NC + c];   // self loop
    float s0 = 0.f, s1 = 0.f, s2 = 0.f, s3 = 0.f;
    float s4 = 0.f, s5 = 0.f, s6 = 0.f, s7 = 0.f;
    int lim8 = lim & ~7;
    for (int ep = 0; ep < lim8; ep += 8) {
        int4 e0 = ec4[(ep >> 2) + 0];
        int4 e1 = ec4[(ep >> 2) + 1];
        s0 += hs_in[e0.x * NC + c];
        s1 += hs_in[e0.y * NC + c];
        s2 += hs_in[e0.z * NC + c];
        s3 += hs_in[e0.w * NC + c];
        s4 += hs_in[e1.x * NC + c];
        s5 += hs_in[e1.y * NC + c];
        s6 += hs_in[e1.z * NC + c];
        s7 += hs_in[e1.w * NC + c];
    }
    for (int ep = lim8; ep < lim; ++ep) acc += hs_in[ec[ep] * NC + c];
    acc += ((s0 + s1) + (s2 + s3)) + ((s4 + s5) + (s6 + s7));
    int m = *ovf_cnt;
    if (m > 0) {   // parachute: expected never taken
        if (m > OVF_CAP) m = OVF_CAP;
        for (int i = 0; i < m; ++i) {
            int2 p = ovf[i];
            if (p.x == row) acc += hs_in[p.y * NC + c];
        }
    }
    float hn = 0.9f * d * acc + 0.1f * beta[row * NC + c];
    hs_out[row * NC + c] = d * hn;
}

__global__ void k_final(const float* __restrict__ hs, const float* __restrict__ dis,
        float* __restrict__ out_alpha, float* __restrict__ out_probs, int n) {
    int i = blockIdx.x * blockDim.x + threadIdx.x;
    if (i >= n) return;
    float inv_d = 1.f / dis[i];
    float a[NC];
    float s = 0.f;
    #pragma unroll
    for (int c = 0; c < NC; ++c) {
        float v = hs[(size_t)i * NC + c] * inv_d;
        v = 0.001f + fmaxf(v, 0.f);
        a[c] = v; s += v;
    }
    float inv = 1.f / s;
    #pragma unroll
    for (int c = 0; c < NC; ++c) {
        out_alpha[(size_t)i * NC + c] = a[c];
        out_probs[(size_t)i * NC + c] = a[c] * inv;
    }
}

extern "C" void kernel_launch(void* const* d_in, const int* in_sizes, int n_in,
                              void* d_out, int out_size, void* d_ws, size_t ws_size,
                              hipStream_t stream) {
    const float* x   = (const float*)d_in[0];
    const int*   ei  = (const int*)d_in[1];
    const float* W1  = (const float*)d_in[2];
    const float* b1  = (const float*)d_in[3];
    const float* g1  = (const float*)d_in[4];
    const float* be1 = (const float*)d_in[5];
    const float* W2  = (const float*)d_in[6];
    const float* b2  = (const float*)d_in[7];
    const float* g2  = (const float*)d_in[8];
    const float* be2 = (const float*)d_in[9];
    const float* W3  = (const float*)d_in[10];
    const float* b3  = (const float*)d_in[11];
    const float* x0  = (const float*)d_in[12];
    const float* ap  = (const float*)d_in[13];
    const float* bp  = (const float*)d_in[14];
    const float* mu  = (const float*)d_in[15];
    const float* lv  = (const float*)d_in[16];

    int n = in_sizes[0] / NFEAT_IN;   // 100000
    int e = in_sizes[1] / 2;          // 3200000
    const int* rows = ei;
    const int* cols = ei + e;
    int rpb = (n + NB - 1) / NB;      // 782 rows per bucket
    int cap = (e + e / 16) / NB;      // pairs/bucket (+~10 sigma slack)

    size_t an = (size_t)HDIM * n;
    float* ws  = (float*)d_ws;
    float* t1t = ws;                         // 64n floats; later ecol (64n ints)
    float* t2t = ws + an;                    // 64n floats; later bucket pairs
    int2*  bpairs = (int2*)t2t;              // NB*cap int2
    float* stats = (float*)((char*)t2t + (size_t)NB * cap * sizeof(int2));
    float *sum1 = stats,       *sq1 = stats + 64,  *A1 = stats + 128, *B1 = stats + 192;
    float *sum2 = stats + 256, *sq2 = stats + 320, *A2 = stats + 384, *B2 = stats + 448;
    int*  bcnt    = (int*)(stats + 512);     // NB
    int*  ovf_cnt = bcnt + NB;               // 1 (+pad)
    int2* ovf     = (int2*)(ovf_cnt + 4);    // OVF_CAP int2
    int*   cur = (int*)(ovf + OVF_CAP);      // n ints
    float* dis = (float*)(cur + n);          // n floats
    float* hs0 = (float*)bpairs;             // overlays dead bucket region
    float* hs1 = hs0 + (size_t)NC * n;
    int* ecol = (int*)t1t;

    float* out = (float*)d_out;
    float* out_alpha = out;
    float* out_probs = out + (size_t)n * NC;
    float* out_z     = out + (size_t)2 * n * NC;
    float* out_beta  = out_z + (size_t)n * DLAT;
    float* out_logq  = out_beta + (size_t)n * NC;

    int nb_nodes = (n + 255) / 256;
    int nb_gemm1 = (n + BM1 - 1) / BM1;
    int nb_gemm  = (n + BM - 1) / BM;
    int nb_nc    = (int)(((size_t)n * NC + 255) / 256);

    (void)hipMemsetAsync(stats, 0, (512 + NB + 4) * sizeof(float), stream);

    // encoder
    k_gemm1<<<nb_gemm1, 256, 0, stream>>>(x, W1, b1, t1t, n);
    k_stats<<<HDIM * 8, 256, 0, stream>>>(t1t, sum1, sq1, n);
    k_finalize<<<1, 64, 0, stream>>>(sum1, sq1, g1, be1, A1, B1, n);
    k_gemm2<<<nb_gemm, 256, 0, stream>>>(t1t, A1, B1, W2, b2, t2t, n);
    k_stats<<<HDIM * 8, 256, 0, stream>>>(t2t, sum2, sq2, n);
    k_finalize<<<1, 64, 0, stream>>>(sum2, sq2, g2, be2, A2, B2, n);
    k_zlin<<<nb_nodes, 256, 0, stream>>>(t2t, A2, B2, W3, b3, out_z, n);
    k_flow<<<nb_nc, 256, 0, stream>>>(out_z, x0, ap, bp, mu, lv,
                                      out_logq, out_beta, n);

    // graph build: radix partition then per-bucket ELL placement
    (void)hipMemsetAsync(cur, 0, (size_t)n * sizeof(int), stream);
    int nt_bucket = (e + TILE - 1) / TILE;
    k_bucket<<<nt_bucket, 256, 0, stream>>>(rows, cols, bpairs, bcnt, cap,
                                            cur, ovf, ovf_cnt, e, n, rpb);
    k_build<<<NB, 256, 0, stream>>>(bpairs, bcnt, cap, ecol, cur, ovf, ovf_cnt, n, rpb);
    k_dis<<<nb_nodes, 256, 0, stream>>>(cur, dis, n);
    k_init_hs<<<nb_nodes, 256, 0, stream>>>(out_beta, dis, hs0, n);

    // APPNP: 10 gather rounds on hs only, ping-pong hs0/hs1
    for (int it = 0; it < KPROP; ++it) {
        const float* hin = (it & 1) ? hs1 : hs0;
        float* hso = (it & 1) ? hs0 : hs1;
        k_gather<<<nb_nc, 256, 0, stream>>>(cur, ecol, hin, out_beta, dis,
                                            hso, ovf, ovf_cnt, n);
    }
    k_final<<<nb_nodes, 256, 0, stream>>>(hs0, dis, out_alpha, out_probs, n);
}

// Round 13
// 510.339 us; speedup vs baseline: 1.0255x; 1.0255x over previous
//
#include <hip/hip_runtime.h>

#define NFEAT_IN 256
#define HDIM 64
#define DLAT 16
#define NC 8
#define NL 10
#define KPROP 10
#define ELLW 64
#define OVF_CAP 8192
#define NB 128          // row-range buckets
#define PERTHREAD 16
#define TILE (256 * PERTHREAD)
#define BM 64           // GEMM row tile
#define BK1 32          // GEMM k tile

__device__ __forceinline__ float softplusf(float x) {
    return (x > 20.f) ? x : log1pf(expf(x));
}

// 4 rows x 4 cols of FMAs: acc[i][j] += a_i * wv_j
__device__ __forceinline__ void fma16(float a0, float a1, float a2, float a3,
                                      const float4 wv, float acc[4][4]) {
    acc[0][0] = fmaf(a0, wv.x, acc[0][0]); acc[0][1] = fmaf(a0, wv.y, acc[0][1]);
    acc[0][2] = fmaf(a0, wv.z, acc[0][2]); acc[0][3] = fmaf(a0, wv.w, acc[0][3]);
    acc[1][0] = fmaf(a1, wv.x, acc[1][0]); acc[1][1] = fmaf(a1, wv.y, acc[1][1]);
    acc[1][2] = fmaf(a1, wv.z, acc[1][2]); acc[1][3] = fmaf(a1, wv.w, acc[1][3]);
    acc[2][0] = fmaf(a2, wv.x, acc[2][0]); acc[2][1] = fmaf(a2, wv.y, acc[2][1]);
    acc[2][2] = fmaf(a2, wv.z, acc[2][2]); acc[2][3] = fmaf(a2, wv.w, acc[2][3]);
    acc[3][0] = fmaf(a3, wv.x, acc[3][0]); acc[3][1] = fmaf(a3, wv.y, acc[3][1]);
    acc[3][2] = fmaf(a3, wv.z, acc[3][2]); acc[3][3] = fmaf(a3, wv.w, acc[3][3]);
}

// ---------------- GEMM1: x[n][256] @ W1[256][64] + b1 -> t1t[64][n] ----------
// r10 known-good form: BM=64, scalar-broadcast A reads.
__global__ __launch_bounds__(256) void k_gemm1(
        const float* __restrict__ x, const float* __restrict__ W1,
        const float* __restrict__ b1, float* __restrict__ t1t, int n) {
    __shared__ float xs[BM][BK1 + 4];   // 64 x 36
    __shared__ float ws[BK1][HDIM];     // 32 x 64
    int t = threadIdx.x;
    int row0 = blockIdx.x * BM;
    int tr = t >> 4, tc = t & 15;       // 16x16 thread grid; 4x4 micro-tile
    float acc[4][4];
    float4 bv = *reinterpret_cast<const float4*>(&b1[tc * 4]);
    #pragma unroll
    for (int i = 0; i < 4; ++i) {
        acc[i][0] = bv.x; acc[i][1] = bv.y; acc[i][2] = bv.z; acc[i][3] = bv.w;
    }
    for (int k0 = 0; k0 < NFEAT_IN; k0 += BK1) {
        __syncthreads();
        #pragma unroll
        for (int it = 0; it < 2; ++it) {
            int i = it * 256 + t;
            int row = i >> 3, qq = i & 7;
            int grow = row0 + row;
            float4 v = make_float4(0.f, 0.f, 0.f, 0.f);
            if (grow < n)
                v = *reinterpret_cast<const float4*>(
                        &x[(size_t)grow * NFEAT_IN + k0 + qq * 4]);
            *reinterpret_cast<float4*>(&xs[row][qq * 4]) = v;
        }
        #pragma unroll
        for (int it = 0; it < 2; ++it) {
            int i = it * 256 + t;
            int kk = i >> 4, qq = i & 15;
            *reinterpret_cast<float4*>(&ws[kk][qq * 4]) =
                *reinterpret_cast<const float4*>(&W1[(size_t)(k0 + kk) * HDIM + qq * 4]);
        }
        __syncthreads();
        #pragma unroll 8
        for (int kk = 0; kk < BK1; ++kk) {
            float a0 = xs[tr * 4 + 0][kk];
            float a1 = xs[tr * 4 + 1][kk];
            float a2 = xs[tr * 4 + 2][kk];
            float a3 = xs[tr * 4 + 3][kk];
            float4 w = *reinterpret_cast<const float4*>(&ws[kk][tc * 4]);
            fma16(a0, a1, a2, a3, w, acc);
        }
    }
    int r = row0 + tr * 4;
    if (r < n) {
        #pragma unroll
        for (int cj = 0; cj < 4; ++cj) {
            int j = tc * 4 + cj;
            float4 v = make_float4(acc[0][cj], acc[1][cj], acc[2][cj], acc[3][cj]);
            *reinterpret_cast<float4*>(&t1t[(size_t)j * n + r]) = v;
        }
    }
}

// ---------------- GEMM2: relu(bn1(t1)) @ W2 + b2 -> t2t[64][n] --------------
__global__ __launch_bounds__(256) void k_gemm2(
        const float* __restrict__ t1t, const float* __restrict__ A1,
        const float* __restrict__ B1, const float* __restrict__ W2,
        const float* __restrict__ b2, float* __restrict__ t2t, int n) {
    __shared__ float xs[BK1][BM + 4];   // 32 x 68
    __shared__ float ws[BK1][HDIM];     // 32 x 64
    __shared__ float As[HDIM], Bs[HDIM];
    int t = threadIdx.x;
    int row0 = blockIdx.x * BM;
    if (t < HDIM) { As[t] = A1[t]; Bs[t] = B1[t]; }
    int tr = t >> 4, tc = t & 15;
    float acc[4][4];
    float4 bv = *reinterpret_cast<const float4*>(&b2[tc * 4]);
    #pragma unroll
    for (int i = 0; i < 4; ++i) {
        acc[i][0] = bv.x; acc[i][1] = bv.y; acc[i][2] = bv.z; acc[i][3] = bv.w;
    }
    for (int k0 = 0; k0 < HDIM; k0 += BK1) {
        __syncthreads();
        #pragma unroll
        for (int it = 0; it < 2; ++it) {
            int i = it * 256 + t;
            int kk = i >> 4, qq = i & 15;
            float4 v = make_float4(0.f, 0.f, 0.f, 0.f);
            if (row0 + qq * 4 < n) {
                v = *reinterpret_cast<const float4*>(
                        &t1t[(size_t)(k0 + kk) * n + row0 + qq * 4]);
                float a = As[k0 + kk], b = Bs[k0 + kk];
                v.x = fmaxf(fmaf(a, v.x, b), 0.f);
                v.y = fmaxf(fmaf(a, v.y, b), 0.f);
                v.z = fmaxf(fmaf(a, v.z, b), 0.f);
                v.w = fmaxf(fmaf(a, v.w, b), 0.f);
            }
            *reinterpret_cast<float4*>(&xs[kk][qq * 4]) = v;
        }
        #pragma unroll
        for (int it = 0; it < 2; ++it) {
            int i = it * 256 + t;
            int kk = i >> 4, qq = i & 15;
            *reinterpret_cast<float4*>(&ws[kk][qq * 4]) =
                *reinterpret_cast<const float4*>(&W2[(size_t)(k0 + kk) * HDIM + qq * 4]);
        }
        __syncthreads();
        #pragma unroll 8
        for (int kk = 0; kk < BK1; ++kk) {
            float4 a = *reinterpret_cast<const float4*>(&xs[kk][tr * 4]);
            float4 w = *reinterpret_cast<const float4*>(&ws[kk][tc * 4]);
            fma16(a.x, a.y, a.z, a.w, w, acc);
        }
    }
    int r = row0 + tr * 4;
    if (r < n) {
        #pragma unroll
        for (int cj = 0; cj < 4; ++cj) {
            int j = tc * 4 + cj;
            float4 v = make_float4(acc[0][cj], acc[1][cj], acc[2][cj], acc[3][cj]);
            *reinterpret_cast<float4*>(&t2t[(size_t)j * n + r]) = v;
        }
    }
}

// per-feature sum & sumsq over transposed activations [64][n]
__global__ __launch_bounds__(256) void k_stats(
        const float* __restrict__ tt, float* __restrict__ sum,
        float* __restrict__ sq, int n) {
    int feat = blockIdx.x >> 3;
    int chunk = blockIdx.x & 7;
    const float4* p = reinterpret_cast<const float4*>(tt + (size_t)feat * n);
    int n4 = n / 4;
    float s = 0.f, q = 0.f;
    for (int i = chunk * 256 + threadIdx.x; i < n4; i += 8 * 256) {
        float4 v = p[i];
        s += v.x + v.y + v.z + v.w;
        q += v.x * v.x + v.y * v.y + v.z * v.z + v.w * v.w;
    }
    if (chunk == 0 && threadIdx.x < (n & 3)) {
        float v = tt[(size_t)feat * n + (n & ~3) + threadIdx.x];
        s += v; q += v * v;
    }
    #pragma unroll
    for (int off = 32; off; off >>= 1) {
        s += __shfl_down(s, off, 64);
        q += __shfl_down(q, off, 64);
    }
    __shared__ float ls[4], lq[4];
    int wid = threadIdx.x >> 6, lane = threadIdx.x & 63;
    if (lane == 0) { ls[wid] = s; lq[wid] = q; }
    __syncthreads();
    if (threadIdx.x == 0) {
        atomicAdd(&sum[feat], ls[0] + ls[1] + ls[2] + ls[3]);
        atomicAdd(&sq[feat],  lq[0] + lq[1] + lq[2] + lq[3]);
    }
}

__global__ void k_finalize(const float* __restrict__ sum, const float* __restrict__ sq,
        const float* __restrict__ g, const float* __restrict__ be,
        float* __restrict__ A, float* __restrict__ B, int n) {
    int j = threadIdx.x;
    if (j >= HDIM) return;
    float mean = sum[j] / (float)n;
    float var = sq[j] / (float)n - mean * mean;
    float istd = 1.0f / sqrtf(var + 1e-5f);
    A[j] = g[j] * istd;
    B[j] = be[j] - mean * istd * g[j];
}

// ---------------- z = relu(bn2(t2)) @ W3 + b3 (GEMV per node) ----------------
__global__ __launch_bounds__(256) void k_zlin(
        const float* __restrict__ t2t, const float* __restrict__ A2,
        const float* __restrict__ B2, const float* __restrict__ W3,
        const float* __restrict__ b3, float* __restrict__ out_z, int n) {
    __shared__ float As[HDIM], Bs[HDIM], Ws[HDIM * DLAT];
    int t = threadIdx.x;
    if (t < HDIM) { As[t] = A2[t]; Bs[t] = B2[t]; }
    for (int i = t; i < HDIM * DLAT; i += 256) Ws[i] = W3[i];
    __syncthreads();
    int row = blockIdx.x * 256 + t;
    if (row >= n) return;
    float z[DLAT];
    #pragma unroll
    for (int j = 0; j < DLAT; ++j) z[j] = b3[j];
    for (int k = 0; k < HDIM; ++k) {
        float hv = fmaxf(fmaf(As[k], t2t[(size_t)k * n + row], Bs[k]), 0.f);
        const float* w = &Ws[k * DLAT];
        #pragma unroll
        for (int j = 0; j < DLAT; ++j) z[j] = fmaf(hv, w[j], z[j]);
    }
    float4* zp = reinterpret_cast<float4*>(&out_z[(size_t)row * DLAT]);
    zp[0] = make_float4(z[0], z[1], z[2], z[3]);
    zp[1] = make_float4(z[4], z[5], z[6], z[7]);
    zp[2] = make_float4(z[8], z[9], z[10], z[11]);
    zp[3] = make_float4(z[12], z[13], z[14], z[15]);
}

// ---------------- radial flow: one thread per (node, class) ----------------
__global__ __launch_bounds__(256) void k_flow(
        const float* __restrict__ zbuf, const float* __restrict__ x0,
        const float* __restrict__ ap, const float* __restrict__ bp,
        const float* __restrict__ mu, const float* __restrict__ lv,
        float* __restrict__ out_logq, float* __restrict__ out_beta, int n) {
    __shared__ float a_s[NL * NC], b_s[NL * NC];
    __shared__ float x0_s[NL * NC][DLAT + 1];
    __shared__ float mu_s[NC][DLAT + 1], iv_s[NC][DLAT + 1], slv_s[NC];
    int t = threadIdx.x;
    for (int i = t; i < NL * NC; i += 256) {
        float a = softplusf(ap[i]);
        a_s[i] = a;
        b_s[i] = softplusf(bp[i]) - a;
    }
    for (int i = t; i < NL * NC * DLAT; i += 256) x0_s[i >> 4][i & 15] = x0[i];
    for (int i = t; i < NC * DLAT; i += 256) {
        mu_s[i >> 4][i & 15] = mu[i];
        iv_s[i >> 4][i & 15] = __expf(-lv[i]);
    }
    if (t < NC) {
        float s = 0.f;
        for (int d = 0; d < DLAT; ++d) s += lv[t * DLAT + d];
        slv_s[t] = s;
    }
    __syncthreads();
    int gid = blockIdx.x * 256 + t;
    int row = gid >> 3, c = gid & 7;
    if (row >= n) return;
    float zz[DLAT];
    const float4* zp = reinterpret_cast<const float4*>(&zbuf[(size_t)row * DLAT]);
    float4 z0 = zp[0], z1 = zp[1], z2 = zp[2], z3 = zp[3];
    zz[0] = z0.x; zz[1] = z0.y; zz[2] = z0.z; zz[3] = z0.w;
    zz[4] = z1.x; zz[5] = z1.y; zz[6] = z1.z; zz[7] = z1.w;
    zz[8] = z2.x; zz[9] = z2.y; zz[10] = z2.z; zz[11] = z2.w;
    zz[12] = z3.x; zz[13] = z3.y; zz[14] = z3.z; zz[15] = z3.w;

    float log_det = 0.f;
    #pragma unroll
    for (int l = NL - 1; l >= 0; --l) {
        int idx = l * NC + c;
        float a = a_s[idx], b = b_s[idx];
        const float* x0p = x0_s[idx];
        float diff[DLAT];
        float r2 = 0.f;
        #pragma unroll
        for (int d = 0; d < DLAT; ++d) {
            diff[d] = zz[d] - x0p[d];
            r2 = fmaf(diff[d], diff[d], r2);
        }
        float r = fmaxf(sqrtf(r2), 1e-8f);
        float h = 1.f / (a + r);
        float bh = b * h;
        #pragma unroll
        for (int d = 0; d < DLAT; ++d) zz[d] = fmaf(bh, diff[d], zz[d]);
        log_det += (DLAT - 1) * __logf(1.f + bh) + __logf(1.f + bh - bh * h * r);
    }
    float quad = 0.f;
    #pragma unroll
    for (int d = 0; d < DLAT; ++d) {
        float dd = zz[d] - mu_s[c][d];
        quad = fmaf(dd * dd, iv_s[c][d], quad);
    }
    float lq = -14.70301653f - 0.5f * slv_s[c] - 0.5f * quad + log_det;
    out_logq[gid] = lq;
    float w = fminf(fmaxf(lq + 20.24819398f, -30.f), 30.f);
    out_beta[gid] = __expf(w);
}

// ---------------- pass 1: radix partition edges into NB row-range buckets ----
__global__ __launch_bounds__(256) void k_bucket(
        const int* __restrict__ rows, const int* __restrict__ cols,
        int2* __restrict__ bpairs, int* __restrict__ bcnt, int cap,
        int* __restrict__ cur, int2* __restrict__ ovf, int* __restrict__ ovf_cnt,
        int e, int n, int rpb) {
    __shared__ int lcnt[NB], loff[NB], lcur[NB], gbase[NB], sc[NB];
    __shared__ int2 staged[TILE];
    int t = threadIdx.x;
    int base = blockIdx.x * TILE;
    for (int i = t; i < NB; i += 256) lcnt[i] = 0;
    __syncthreads();
    int er[PERTHREAD], ec[PERTHREAD], eb[PERTHREAD];
    #pragma unroll
    for (int k = 0; k < PERTHREAD; ++k) {
        int i = base + k * 256 + t;
        eb[k] = -1;
        if (i < e) {
            int r = rows[i], c = cols[i];
            if ((unsigned)r < (unsigned)n && (unsigned)c < (unsigned)n) {
                er[k] = r; ec[k] = c;
                int b = (int)((unsigned)r / (unsigned)rpb);
                eb[k] = b;
                atomicAdd(&lcnt[b], 1);
            }
        }
    }
    __syncthreads();
    if (t < NB) sc[t] = lcnt[t];
    __syncthreads();
    for (int off = 1; off < NB; off <<= 1) {
        int v = 0;
        if (t < NB && t >= off) v = sc[t - off];
        __syncthreads();
        if (t < NB) sc[t] += v;
        __syncthreads();
    }
    if (t < NB) { loff[t] = sc[t] - lcnt[t]; lcur[t] = sc[t] - lcnt[t]; }
    __syncthreads();
    #pragma unroll
    for (int k = 0; k < PERTHREAD; ++k) {
        if (eb[k] >= 0) {
            int slot = atomicAdd(&lcur[eb[k]], 1);
            staged[slot] = make_int2(er[k], ec[k]);
        }
    }
    __syncthreads();
    if (t < NB && lcnt[t] > 0) gbase[t] = atomicAdd(&bcnt[t], lcnt[t]);
    __syncthreads();
    int wid = t >> 6, lane = t & 63;
    for (int b = wid; b < NB; b += 4) {
        int cnt = lcnt[b];
        if (!cnt) continue;
        int gb = gbase[b], lo = loff[b];
        for (int k = lane; k < cnt; k += 64) {
            int2 p = staged[lo + k];
            int dst = gb + k;
            if (dst < cap) {
                bpairs[(size_t)b * cap + dst] = p;
            } else {
                int o = atomicAdd(ovf_cnt, 1);
                if (o < OVF_CAP) ovf[o] = p;
                atomicAdd(&cur[p.x], 1);
            }
        }
    }
}

// ---------------- pass 2: per-bucket ELL placement (L2-local writes) --------
__global__ __launch_bounds__(256) void k_build(
        const int2* __restrict__ bpairs, const int* __restrict__ bcnt, int cap,
        int* __restrict__ ecol, int* __restrict__ cur,
        int2* __restrict__ ovf, int* __restrict__ ovf_cnt, int n, int rpb) {
    __shared__ int lcnt[1024];
    int b = blockIdx.x, t = threadIdx.x;
    int row_base = b * rpb;
    int nrows = n - row_base; if (nrows > rpb) nrows = rpb;
    if (nrows <= 0) return;
    for (int i = t; i < nrows; i += 256) lcnt[i] = 0;
    __syncthreads();
    int m = bcnt[b]; if (m > cap) m = cap;
    const int2* bp = bpairs + (size_t)b * cap;
    for (int i = t; i < m; i += 256) {
        int2 p = bp[i];
        int lr = p.x - row_base;
        int j = atomicAdd(&lcnt[lr], 1);
        if (j < ELLW) {
            ecol[(size_t)p.x * ELLW + j] = p.y;
        } else {
            int o = atomicAdd(ovf_cnt, 1);
            if (o < OVF_CAP) ovf[o] = p;
        }
    }
    __syncthreads();
    for (int i = t; i < nrows; i += 256) {
        int c = lcnt[i];
        if (c) cur[row_base + i] += c;
    }
}

// dis = rsqrt(deg+1); hs0 = dis * beta   (fused)
__global__ void k_disinit(const int* __restrict__ cur, const float* __restrict__ beta,
                          float* __restrict__ dis, float* __restrict__ hs, int n) {
    int i = blockIdx.x * blockDim.x + threadIdx.x;
    if (i >= n) return;
    float d = rsqrtf((float)cur[i] + 1.0f);
    dis[i] = d;
    const float4* b = reinterpret_cast<const float4*>(beta + (size_t)i * NC);
    float4* o = reinterpret_cast<float4*>(hs + (size_t)i * NC);
    float4 b0 = b[0], b1 = b[1];
    o[0] = make_float4(d * b0.x, d * b0.y, d * b0.z, d * b0.w);
    o[1] = make_float4(d * b1.x, d * b1.y, d * b1.z, d * b1.w);
}

// ---------------- APPNP gather iteration (8 lanes/row, hs-only state) -------
__global__ __launch_bounds__(256) void k_gather(
        const int* __restrict__ cur, const int* __restrict__ ecol,
        const float* __restrict__ hs_in, const float* __restrict__ beta,
        const float* __restrict__ dis, float* __restrict__ hs_out,
        const int2* __restrict__ ovf, const int* __restrict__ ovf_cnt, int n) {
    int row = (blockIdx.x * blockDim.x + threadIdx.x) >> 3;
    int c = threadIdx.x & 7;
    if (row >= n) return;
    int cnt = cur[row];
    int lim = cnt < ELLW ? cnt : ELLW;
    float d = dis[row];
    const int* ec = ecol + (size_t)row * ELLW;
    const int4* ec4 = reinterpret_cast<const int4*>(ec);
    float acc = hs_in[row * NC + c];   // self loop
    float s0 = 0.f, s1 = 0.f, s2 = 0.f, s3 = 0.f;
    float s4 = 0.f, s5 = 0.f, s6 = 0.f, s7 = 0.f;
    int lim8 = lim & ~7;
    for (int ep = 0; ep < lim8; ep += 8) {
        int4 e0 = ec4[(ep >> 2) + 0];
        int4 e1 = ec4[(ep >> 2) + 1];
        s0 += hs_in[e0.x * NC + c];
        s1 += hs_in[e0.y * NC + c];
        s2 += hs_in[e0.z * NC + c];
        s3 += hs_in[e0.w * NC + c];
        s4 += hs_in[e1.x * NC + c];
        s5 += hs_in[e1.y * NC + c];
        s6 += hs_in[e1.z * NC + c];
        s7 += hs_in[e1.w * NC + c];
    }
    for (int ep = lim8; ep < lim; ++ep) acc += hs_in[ec[ep] * NC + c];
    acc += ((s0 + s1) + (s2 + s3)) + ((s4 + s5) + (s6 + s7));
    int m = *ovf_cnt;
    if (m > 0) {   // parachute: expected never taken
        if (m > OVF_CAP) m = OVF_CAP;
        for (int i = 0; i < m; ++i) {
            int2 p = ovf[i];
            if (p.x == row) acc += hs_in[p.y * NC + c];
        }
    }
    float hn = 0.9f * d * acc + 0.1f * beta[row * NC + c];
    hs_out[row * NC + c] = d * hn;
}

// ---------------- final gather: fused alpha/probs epilogue ----------------
__global__ __launch_bounds__(256) void k_gather_final(
        const int* __restrict__ cur, const int* __restrict__ ecol,
        const float* __restrict__ hs_in, const float* __restrict__ beta,
        const float* __restrict__ dis, float* __restrict__ out_alpha,
        float* __restrict__ out_probs,
        const int2* __restrict__ ovf, const int* __restrict__ ovf_cnt, int n) {
    int row = (blockIdx.x * blockDim.x + threadIdx.x) >> 3;
    int c = threadIdx.x & 7;
    if (row >= n) return;
    int cnt = cur[row];
    int lim = cnt < ELLW ? cnt : ELLW;
    float d = dis[row];
    const int* ec = ecol + (size_t)row * ELLW;
    const int4* ec4 = reinterpret_cast<const int4*>(ec);
    float acc = hs_in[row * NC + c];   // self loop
    float s0 = 0.f, s1 = 0.f, s2 = 0.f, s3 = 0.f;
    float s4 = 0.f, s5 = 0.f, s6 = 0.f, s7 = 0.f;
    int lim8 = lim & ~7;
    for (int ep = 0; ep < lim8; ep += 8) {
        int4 e0 = ec4[(ep >> 2) + 0];
        int4 e1 = ec4[(ep >> 2) + 1];
        s0 += hs_in[e0.x * NC + c];
        s1 += hs_in[e0.y * NC + c];
        s2 += hs_in[e0.z * NC + c];
        s3 += hs_in[e0.w * NC + c];
        s4 += hs_in[e1.x * NC + c];
        s5 += hs_in[e1.y * NC + c];
        s6 += hs_in[e1.z * NC + c];
        s7 += hs_in[e1.w * NC + c];
    }
    for (int ep = lim8; ep < lim; ++ep) acc += hs_in[ec[ep] * NC + c];
    acc += ((s0 + s1) + (s2 + s3)) + ((s4 + s5) + (s6 + s7));
    int m = *ovf_cnt;
    if (m > 0) {
        if (m > OVF_CAP) m = OVF_CAP;
        for (int i = 0; i < m; ++i) {
            int2 p = ovf[i];
            if (p.x == row) acc += hs_in[p.y * NC + c];
        }
    }
    float hn = 0.9f * d * acc + 0.1f * beta[row * NC + c];   // final h (not hs)
    float v = 0.001f + fmaxf(hn, 0.f);
    // row-sum over the 8 consecutive channel lanes
    float s = v;
    s += __shfl_xor(s, 1, 64);
    s += __shfl_xor(s, 2, 64);
    s += __shfl_xor(s, 4, 64);
    out_alpha[row * NC + c] = v;
    out_probs[row * NC + c] = v / s;
}

extern "C" void kernel_launch(void* const* d_in, const int* in_sizes, int n_in,
                              void* d_out, int out_size, void* d_ws, size_t ws_size,
                              hipStream_t stream) {
    const float* x   = (const float*)d_in[0];
    const int*   ei  = (const int*)d_in[1];
    const float* W1  = (const float*)d_in[2];
    const float* b1  = (const float*)d_in[3];
    const float* g1  = (const float*)d_in[4];
    const float* be1 = (const float*)d_in[5];
    const float* W2  = (const float*)d_in[6];
    const float* b2  = (const float*)d_in[7];
    const float* g2  = (const float*)d_in[8];
    const float* be2 = (const float*)d_in[9];
    const float* W3  = (const float*)d_in[10];
    const float* b3  = (const float*)d_in[11];
    const float* x0  = (const float*)d_in[12];
    const float* ap  = (const float*)d_in[13];
    const float* bp  = (const float*)d_in[14];
    const float* mu  = (const float*)d_in[15];
    const float* lv  = (const float*)d_in[16];

    int n = in_sizes[0] / NFEAT_IN;   // 100000
    int e = in_sizes[1] / 2;          // 3200000
    const int* rows = ei;
    const int* cols = ei + e;
    int rpb = (n + NB - 1) / NB;      // 782 rows per bucket
    int cap = (e + e / 16) / NB;      // pairs/bucket (+~10 sigma slack)

    size_t an = (size_t)HDIM * n;
    float* ws  = (float*)d_ws;
    float* t1t = ws;                         // 64n floats; later ecol (64n ints)
    float* t2t = ws + an;                    // 64n floats; later bucket pairs
    int2*  bpairs = (int2*)t2t;              // NB*cap int2
    float* stats = (float*)((char*)t2t + (size_t)NB * cap * sizeof(int2));
    float *sum1 = stats,       *sq1 = stats + 64,  *A1 = stats + 128, *B1 = stats + 192;
    float *sum2 = stats + 256, *sq2 = stats + 320, *A2 = stats + 384, *B2 = stats + 448;
    int*  bcnt    = (int*)(stats + 512);     // NB
    int*  ovf_cnt = bcnt + NB;               // 1 (+pad)
    int2* ovf     = (int2*)(ovf_cnt + 4);    // OVF_CAP int2
    int*   cur = (int*)(ovf + OVF_CAP);      // n ints
    float* dis = (float*)(cur + n);          // n floats
    float* hs0 = (float*)bpairs;             // overlays dead bucket region
    float* hs1 = hs0 + (size_t)NC * n;
    int* ecol = (int*)t1t;

    float* out = (float*)d_out;
    float* out_alpha = out;
    float* out_probs = out + (size_t)n * NC;
    float* out_z     = out + (size_t)2 * n * NC;
    float* out_beta  = out_z + (size_t)n * DLAT;
    float* out_logq  = out_beta + (size_t)n * NC;

    int nb_nodes = (n + 255) / 256;
    int nb_gemm  = (n + BM - 1) / BM;
    int nb_nc    = (int)(((size_t)n * NC + 255) / 256);

    (void)hipMemsetAsync(stats, 0, (512 + NB + 4) * sizeof(float), stream);

    // encoder
    k_gemm1<<<nb_gemm, 256, 0, stream>>>(x, W1, b1, t1t, n);
    k_stats<<<HDIM * 8, 256, 0, stream>>>(t1t, sum1, sq1, n);
    k_finalize<<<1, 64, 0, stream>>>(sum1, sq1, g1, be1, A1, B1, n);
    k_gemm2<<<nb_gemm, 256, 0, stream>>>(t1t, A1, B1, W2, b2, t2t, n);
    k_stats<<<HDIM * 8, 256, 0, stream>>>(t2t, sum2, sq2, n);
    k_finalize<<<1, 64, 0, stream>>>(sum2, sq2, g2, be2, A2, B2, n);
    k_zlin<<<nb_nodes, 256, 0, stream>>>(t2t, A2, B2, W3, b3, out_z, n);
    k_flow<<<nb_nc, 256, 0, stream>>>(out_z, x0, ap, bp, mu, lv,
                                      out_logq, out_beta, n);

    // graph build: radix partition then per-bucket ELL placement
    (void)hipMemsetAsync(cur, 0, (size_t)n * sizeof(int), stream);
    int nt_bucket = (e + TILE - 1) / TILE;
    k_bucket<<<nt_bucket, 256, 0, stream>>>(rows, cols, bpairs, bcnt, cap,
                                            cur, ovf, ovf_cnt, e, n, rpb);
    k_build<<<NB, 256, 0, stream>>>(bpairs, bcnt, cap, ecol, cur, ovf, ovf_cnt, n, rpb);
    k_disinit<<<nb_nodes, 256, 0, stream>>>(cur, out_beta, dis, hs0, n);

    // APPNP: 9 hs-space gathers + 1 fused-final gather
    for (int it = 0; it < KPROP - 1; ++it) {
        const float* hin = (it & 1) ? hs1 : hs0;
        float* hso = (it & 1) ? hs0 : hs1;
        k_gather<<<nb_nc, 256, 0, stream>>>(cur, ecol, hin, out_beta, dis,
                                            hso, ovf, ovf_cnt, n);
    }
    // after 9 iters (it=0..8), latest state is in hs1
    k_gather_final<<<nb_nc, 256, 0, stream>>>(cur, ecol, hs1, out_beta, dis,
                                              out_alpha, out_probs, ovf, ovf_cnt, n);
}